// Round 20
// baseline (227.614 us; speedup 1.0000x reference)
//
#include <hip/hip_runtime.h>
#include <hip/hip_bf16.h>
#include <stdint.h>

typedef float f32x4 __attribute__((ext_vector_type(4)));
typedef __bf16 bf16x8 __attribute__((ext_vector_type(8)));
typedef unsigned short ushort8 __attribute__((ext_vector_type(8)));

#define NB 8
#define NS 8192
#define ND 512
#define NM (NB * NS)      // 65536 rows
#define NK 512            // reduction dim

// ---------------- f32 -> bf16 (RNE) ----------------
__device__ __forceinline__ unsigned short f2bf(float f) {
  unsigned u = __float_as_uint(f);
  u += 0x7FFFu + ((u >> 16) & 1u);
  return (unsigned short)(u >> 16);
}

__global__ __launch_bounds__(256) void cvt_bf16(const float* __restrict__ src,
                                                unsigned short* __restrict__ dst,
                                                int n8) {
  int i = blockIdx.x * 256 + threadIdx.x;
  if (i >= n8) return;
  const float4* s = reinterpret_cast<const float4*>(src + (size_t)i * 8);
  float4 v0 = s[0], v1 = s[1];
  ushort8 o;
  o[0] = f2bf(v0.x); o[1] = f2bf(v0.y); o[2] = f2bf(v0.z); o[3] = f2bf(v0.w);
  o[4] = f2bf(v1.x); o[5] = f2bf(v1.y); o[6] = f2bf(v1.z); o[7] = f2bf(v1.w);
  *reinterpret_cast<ushort8*>(dst + (size_t)i * 8) = o;
}

// ---------------- 256x128ch GEMM, BK=32 ring-3 counted-vmcnt (R17 skeleton) ----
// Block: 256 seq rows (= 2 scan chunks) x 128 channels (256 W-rows: 128 hidden
// + 128 gate, mixed B-frag mapping so hid/gat pair in-thread). 8 waves = 2(wm)
// x 4(wn); per-wave acc 8x4 (128 rows x 64 W-rows). 16 kts of BK=32.
// Ring-3 buffers (32KB each: A 16KB | B 16KB). Per kt (ONE phase):
//   READF(C): 12 ds_read_b128; STAGE(S=kt+2): 4 global_load_lds;
//   BAR; lgkmcnt(0)+SB; setprio(1); 32 MFMA; setprio(0);
//   vmcnt(4)+SB (retires kt+1's 4 loads; kt+2's stay in flight; NEVER 0
//   until tail); BAR.
// Overwrite safety: buf S == kt-1's compute buf; its reads drained by kt-1's
// lgkm0 before kt-1's final BAR; kt's stages issue after that BAR.
// Swizzle (64B rows, 4 chunks, 8-lane-phase bank model): store chunk
// c^((row>>1)&3) via pre-swizzled per-lane source; read chunk kg^((fr>>1)&3)
// -> conflict-free. K order = kt ascending -> accumulation bitwise = R19.
// Epilogue: in-reg a/b + packed pk + wave-local chunk aggregates (R19 verified).
__global__ __launch_bounds__(512) void gemm_ab(const unsigned short* __restrict__ xb,
                                               const unsigned short* __restrict__ wb,
                                               uint32_t* __restrict__ pk,
                                               float* __restrict__ aggA,
                                               float* __restrict__ aggB) {
  __shared__ __align__(16) char lds[3 * 32768];   // 96KB: 3 x (A 16KB | B 16KB)

  const int tid = threadIdx.x;
  const int w = tid >> 6;          // 0..7
  const int lane = tid & 63;
  const int wm = w >> 2;           // 0..1 : 128-row half (= scan chunk)
  const int wn = w & 3;            // 0..3 : 32-channel group
  // T1 bijective XCD swizzle: 1024 blocks = 256 mblk x 4 nblk
  const int orig = blockIdx.x;
  const int wg = (orig & 7) * 128 + (orig >> 3);
  const int mblk = wg >> 2;
  const int nblk = wg & 3;
  const int m0 = mblk * 256;
  const int n0 = nblk * 128;       // 128 channels per block

  // staging: slot=(g*8+w)*64+lane, row=slot>>2 (0..255), chunk pos=lane&3.
  // stored chunk c holds global chunk c^((row>>1)&3); (row>>1)&3 == (lane>>3)&3
  const int cg = ((lane & 3) ^ ((lane >> 3) & 3)) << 3;   // source col (bf16)
  const unsigned short* pA2[2];
  const unsigned short* pB2[2];
#pragma unroll
  for (int g = 0; g < 2; ++g) {
    int row = (g * 8 + w) * 16 + (lane >> 2);
    pA2[g] = xb + (size_t)(m0 + row) * NK + cg;
    int e = (row < 128) ? (n0 + row) : (384 + n0 + row);  // hidden | gate W-rows
    pB2[g] = wb + (size_t)e * NK + cg;
  }

  const int fr = lane & 15;
  const int kg = lane >> 4;
  const int rsw = ((kg ^ ((fr >> 1) & 3)) << 4);   // read-side chunk swizzle (bytes)

  f32x4 acc[8][4];
#pragma unroll
  for (int i = 0; i < 8; ++i)
#pragma unroll
    for (int j = 0; j < 4; ++j) acc[i][j] = (f32x4)0.0f;

  bf16x8 af[8], bfr[4];

#define GLD(SRC, DSTOFF)                                                      \
  __builtin_amdgcn_global_load_lds(                                           \
      (const __attribute__((address_space(1))) void*)(SRC),                   \
      (__attribute__((address_space(3))) void*)(lds + (DSTOFF)), 16, 0, 0)

#define STAGE(S, KT)                                                          \
  {                                                                           \
    GLD(pA2[0] + (KT) * 32, (S) * 32768 + (0 * 8 + w) * 1024);                \
    GLD(pA2[1] + (KT) * 32, (S) * 32768 + (1 * 8 + w) * 1024);                \
    GLD(pB2[0] + (KT) * 32, (S) * 32768 + 16384 + (0 * 8 + w) * 1024);        \
    GLD(pB2[1] + (KT) * 32, (S) * 32768 + 16384 + (1 * 8 + w) * 1024);        \
  }

#define READF(C)                                                              \
  {                                                                           \
    const char* ldsA_ = lds + (C) * 32768;                                    \
    const char* ldsB_ = ldsA_ + 16384;                                        \
    _Pragma("unroll")                                                         \
    for (int i = 0; i < 8; ++i) {                                             \
      int rowA = wm * 128 + i * 16 + fr;                                      \
      af[i] = *reinterpret_cast<const bf16x8*>(ldsA_ + rowA * 64 + rsw);      \
    }                                                                         \
    _Pragma("unroll")                                                         \
    for (int n = 0; n < 4; ++n) {                                             \
      int rowB = ((n < 2) ? (wn * 32 + n * 16) : (128 + wn * 32 + (n - 2) * 16)) + fr; \
      bfr[n] = *reinterpret_cast<const bf16x8*>(ldsB_ + rowB * 64 + rsw);     \
    }                                                                         \
  }

#define MFMA32()                                                              \
  {                                                                           \
    _Pragma("unroll")                                                         \
    for (int i = 0; i < 8; ++i)                                               \
      _Pragma("unroll")                                                       \
      for (int j = 0; j < 4; ++j)                                             \
        acc[i][j] = __builtin_amdgcn_mfma_f32_16x16x32_bf16(af[i], bfr[j],    \
                                                            acc[i][j], 0, 0, 0); \
  }

#define BAR() __builtin_amdgcn_s_barrier()
#define SB0() __builtin_amdgcn_sched_barrier(0)
#define LGKM0() asm volatile("s_waitcnt lgkmcnt(0)" ::: "memory")
#define VMC(N) asm volatile("s_waitcnt vmcnt(" #N ")" ::: "memory")

// WMODE: 1 -> vmcnt(4) (steady), 2 -> vmcnt(0) (tail), 0 -> none (last)
#define ITER(KT, C, S, DO, WMODE)                                             \
  {                                                                           \
    READF(C);                                                                 \
    if (DO) STAGE(S, (KT) + 2);                                               \
    BAR(); LGKM0(); SB0();                                                    \
    __builtin_amdgcn_s_setprio(1); MFMA32(); __builtin_amdgcn_s_setprio(0);   \
    if (WMODE == 1) { VMC(4); SB0(); }                                        \
    if (WMODE == 2) { VMC(0); SB0(); }                                        \
    BAR();                                                                    \
  }

  // prologue: kt0 -> buf0, kt1 -> buf1 (8 loads); retire kt0's 4, publish
  STAGE(0, 0);
  STAGE(1, 1);
  VMC(4); SB0();
  BAR();

  ITER(0,  0, 2, 1, 1);
  ITER(1,  1, 0, 1, 1);
  ITER(2,  2, 1, 1, 1);
  ITER(3,  0, 2, 1, 1);
  ITER(4,  1, 0, 1, 1);
  ITER(5,  2, 1, 1, 1);
  ITER(6,  0, 2, 1, 1);
  ITER(7,  1, 0, 1, 1);
  ITER(8,  2, 1, 1, 1);
  ITER(9,  0, 2, 1, 1);
  ITER(10, 1, 0, 1, 1);
  ITER(11, 2, 1, 1, 1);
  ITER(12, 0, 2, 1, 1);
  ITER(13, 1, 0, 1, 1);   // stages kt15; end: kt14 retired, kt15 in flight
  ITER(14, 2, 1, 0, 2);   // no stage; vmcnt(0) -> kt15 ready
  ITER(15, 0, 2, 0, 0);   // last

#undef ITER
#undef GLD
#undef STAGE
#undef READF
#undef MFMA32
#undef BAR
#undef SB0
#undef LGKM0
#undef VMC

  // ---------------- epilogue: pure-register a/b + wave-local chunk aggregates ----
  const float LOG2E = 1.44269504f;
#pragma unroll
  for (int n = 0; n < 2; ++n) {
    const int ch = wn * 32 + n * 16 + fr;
    float Am[8], Bm[8];
#pragma unroll
    for (int m = 0; m < 8; ++m) {
      float As = 1.0f, Bs = 0.0f;
#pragma unroll
      for (int r = 0; r < 4; ++r) {
        float hid = acc[m][n][r];
        float gat = acc[m][n + 2][r];
        float ex1 = __builtin_amdgcn_exp2f(gat * LOG2E);      // exp(gat)
        float a = __builtin_amdgcn_rcpf(1.0f + ex1);          // sigmoid(-gate)
        float z = 1.0f - a;                                   // sigmoid(gate)
        float ex2 = __builtin_amdgcn_exp2f(-hid * LOG2E);     // exp(-hid)
        float gn = __builtin_amdgcn_rcpf(1.0f + ex2);         // sigmoid(hid)
        float g = (hid >= 0.0f) ? (hid + 0.5f) : gn;
        float bb = z * g;
        int row = wm * 128 + 16 * m + 4 * kg + r;
        pk[(size_t)(m0 + row) * ND + n0 + ch] =
            ((uint32_t)f2bf(bb) << 16) | (uint32_t)f2bf(a);
        Bs = fmaf(a, Bs, bb);   // ordered: r ascending
        As *= a;
      }
      Am[m] = As; Bm[m] = Bs;
    }
    // ordered affine all-reduce across kg (4-row segments within 16-row groups)
#pragma unroll
    for (int m = 0; m < 8; ++m) {
      float pA_ = __shfl_xor(Am[m], 16);
      float pB_ = __shfl_xor(Bm[m], 16);
      Bm[m] = (kg & 1) ? fmaf(Am[m], pB_, Bm[m]) : fmaf(pA_, Bm[m], pB_);
      Am[m] *= pA_;
      pA_ = __shfl_xor(Am[m], 32);
      pB_ = __shfl_xor(Bm[m], 32);
      Bm[m] = (kg & 2) ? fmaf(Am[m], pB_, Bm[m]) : fmaf(pA_, Bm[m], pB_);
      Am[m] *= pA_;
    }
    // serial over the 8 16-row groups (ascending) -> full 128-row chunk aggregate
    float As = Am[0], Bs = Bm[0];
#pragma unroll
    for (int m = 1; m < 8; ++m) { Bs = fmaf(Am[m], Bs, Bm[m]); As *= Am[m]; }
    if (kg == 0) {
      size_t o = (size_t)(mblk * 2 + wm) * ND + n0 + ch;   // global chunk index
      aggA[o] = As;
      aggB[o] = Bs;
    }
  }
}

// ---------------- scan pass2: prefix + rescan, write out f32 ----------------
__global__ __launch_bounds__(256) void scan_pass2(const uint32_t* __restrict__ pk,
                                                  const float* __restrict__ aggA,
                                                  const float* __restrict__ aggB,
                                                  float* __restrict__ out,
                                                  float* __restrict__ nextp) {
  int bid = blockIdx.x;
  int b = bid >> 6;
  int c = bid & 63;
  int d2 = threadIdx.x;        // channel-pair 0..255

  float h0 = 0.0f, h1 = 0.0f;
  for (int cc = 0; cc < c; ++cc) {
    int o = (b * 64 + cc) * ND + d2 * 2;
    float2 Aa = *reinterpret_cast<const float2*>(&aggA[o]);
    float2 Bb = *reinterpret_cast<const float2*>(&aggB[o]);
    h0 = fmaf(Aa.x, h0, Bb.x);
    h1 = fmaf(Aa.y, h1, Bb.y);
  }
  size_t base = (size_t)(b * NS + c * 128) * ND + d2 * 2;
#pragma unroll 4
  for (int t = 0; t < 128; ++t) {
    size_t idx = base + (size_t)t * ND;
    uint2 v = *reinterpret_cast<const uint2*>(pk + idx);
    float a0 = __uint_as_float(v.x << 16);
    float b0 = __uint_as_float(v.x & 0xffff0000u);
    float a1 = __uint_as_float(v.y << 16);
    float b1 = __uint_as_float(v.y & 0xffff0000u);
    h0 = fmaf(a0, h0, b0);
    h1 = fmaf(a1, h1, b1);
    *reinterpret_cast<float2*>(&out[idx]) = make_float2(h0, h1);
  }
  if (c == 63) {
    *reinterpret_cast<float2*>(&nextp[b * ND + d2 * 2]) = make_float2(h0, h1);
  }
}

// ---------------- launcher ----------------
extern "C" void kernel_launch(void* const* d_in, const int* in_sizes, int n_in,
                              void* d_out, int out_size, void* d_ws, size_t ws_size,
                              hipStream_t stream) {
  const float* x = (const float*)d_in[0];   // (8, 8192, 512) f32
  const float* W = (const float*)d_in[1];   // (1024, 512) f32
  float* out = (float*)d_out;               // 33554432 + 4096 f32

  char* ws = (char*)d_ws;
  unsigned short* xb  = (unsigned short*)ws;                              // 64 MB
  unsigned short* wbf = (unsigned short*)(ws + (size_t)64 * 1024 * 1024); // 1 MB
  uint32_t* pk = (uint32_t*)(ws + (size_t)65 * 1024 * 1024);              // 128 MB
  float* aggA = (float*)(ws + (size_t)193 * 1024 * 1024);                 // 1 MB
  float* aggB = (float*)(ws + (size_t)194 * 1024 * 1024);                 // 1 MB
  float* nextp = out + (size_t)NM * ND;

  cvt_bf16<<<16384, 256, 0, stream>>>(x, xb, (NM * NK) / 8);
  cvt_bf16<<<256, 256, 0, stream>>>(W, wbf, (1024 * NK) / 8);
  gemm_ab<<<1024, 512, 0, stream>>>(xb, wbf, pk, aggA, aggB);
  scan_pass2<<<512, 256, 0, stream>>>(pk, aggA, aggB, out, nextp);
}

// Round 21
// 194.317 us; speedup vs baseline: 1.1714x; 1.1714x over previous
//
#include <hip/hip_runtime.h>
#include <hip/hip_bf16.h>
#include <stdint.h>

typedef float f32x4 __attribute__((ext_vector_type(4)));
typedef __bf16 bf16x8 __attribute__((ext_vector_type(8)));
typedef unsigned short ushort8 __attribute__((ext_vector_type(8)));

#define NB 8
#define NS 8192
#define ND 512
#define NM (NB * NS)      // 65536 rows
#define NK 512            // reduction dim

// ---------------- helpers ----------------
__device__ __forceinline__ unsigned short f2bf(float f) {
  unsigned u = __float_as_uint(f);
  u += 0x7FFFu + ((u >> 16) & 1u);
  return (unsigned short)(u >> 16);
}

// packed f32x2 -> bf16x2 (RNE)
__device__ __forceinline__ uint32_t cvtpk(float lo, float hi) {
  uint32_t r;
  asm("v_cvt_pk_bf16_f32 %0, %1, %2" : "=v"(r) : "v"(lo), "v"(hi));
  return r;
}

__global__ __launch_bounds__(256) void cvt_bf16(const float* __restrict__ src,
                                                unsigned short* __restrict__ dst,
                                                int n8) {
  int i = blockIdx.x * 256 + threadIdx.x;
  if (i >= n8) return;
  const float4* s = reinterpret_cast<const float4*>(src + (size_t)i * 8);
  float4 v0 = s[0], v1 = s[1];
  ushort8 o;
  o[0] = f2bf(v0.x); o[1] = f2bf(v0.y); o[2] = f2bf(v0.z); o[3] = f2bf(v0.w);
  o[4] = f2bf(v1.x); o[5] = f2bf(v1.y); o[6] = f2bf(v1.z); o[7] = f2bf(v1.w);
  *reinterpret_cast<ushort8*>(dst + (size_t)i * 8) = o;
}

// ---------------- 256x128ch GEMM, f32-A direct staging (kills cvt_x) ----------
// R19's verified big-tile structure with A staged DIRECTLY from f32 x:
// Block: 256 seq rows (= 2 scan chunks) x 128 channels (256 W-rows: 128 hidden
// + 128 gate, mixed B-frags so hid/gat pair in-thread). 8 waves = 2(wm) x 4(wn).
// A: f32, BK=32, dbuf 2 x 32KB (256 rows x 128B, 8 chunks/row), store chunk
//    c <- global chunk c^(row&7) via pre-swizzled per-lane source (R13-proven);
//    read: two f32x4 at chunks (2kg)^(fr&7), (2kg+1)^(fr&7) -> conflict-free
//    (128B rows start at bank 0; chunk permutation per 8-lane phase); cvt_pk
//    to bf16 at the read->MFMA boundary (R13-verified numerics).
// B: bf16, BK=64 pair-buffers dbuf 2 x 32KB, staged every other kt; read at
//    (kk*2+kg*16)^((row&7)<<4) -- R19's measured zero-conflict geometry.
// Sync: R19's never-failed 2-phase: stage(next) FIRST, compute(cur), ONE
// __syncthreads per kt (16 kts). K order ascending -> bitwise = R19.
// Epilogue: in-reg a/b + packed pk + wave-local chunk aggregates (R19 verified).
__global__ __launch_bounds__(512) void gemm_ab(const float* __restrict__ x,
                                               const unsigned short* __restrict__ wb,
                                               uint32_t* __restrict__ pk,
                                               float* __restrict__ aggA,
                                               float* __restrict__ aggB) {
  __shared__ __align__(16) char lds[131072];  // A: 2x32KB @0 | B: 2x32KB @65536

  const int tid = threadIdx.x;
  const int w = tid >> 6;          // 0..7
  const int lane = tid & 63;
  const int wm = w >> 2;           // 0..1 : 128-row half (= scan chunk)
  const int wn = w & 3;            // 0..3 : 32-channel group
  // T1 bijective XCD swizzle: 1024 blocks = 256 mblk x 4 nblk
  const int orig = blockIdx.x;
  const int wg = (orig & 7) * 128 + (orig >> 3);
  const int mblk = wg >> 2;
  const int nblk = wg & 3;
  const int m0 = mblk * 256;
  const int n0 = nblk * 128;       // 128 channels per block

  const int lrow = lane >> 3;      // 0..7
  // A staging: slot=(g*8+w)*64+lane; row=(g*8+w)*8+lrow; chunk=lane&7;
  // source chunk = (lane&7)^lrow  (per-lane constant)
  const int aSrc = (((lane & 7) ^ lrow) << 2);   // f32 elems
  const float* pAf[4];
#pragma unroll
  for (int g = 0; g < 4; ++g) {
    int row = (g * 8 + w) * 8 + lrow;
    pAf[g] = x + (size_t)(m0 + row) * NK + aSrc;
  }
  // B staging (R19): row = g*64 + w*8 + lrow, source col ((lane&7)^lrow)*8 bf16
  const int bSrc = (((lane & 7) ^ lrow) << 3);   // bf16 elems
  const unsigned short* pBf[4];
#pragma unroll
  for (int g = 0; g < 4; ++g) {
    int row = g * 64 + w * 8 + lrow;
    int e = (row < 128) ? (n0 + row) : (384 + n0 + row);  // hidden | gate W-rows
    pBf[g] = wb + (size_t)e * NK + bSrc;
  }

  auto stageA = [&](int buf, int kt) {
    char* base = lds + buf * 32768;
    const int ko = kt << 5;                      // 32 f32 per kt
#pragma unroll
    for (int g = 0; g < 4; ++g)
      __builtin_amdgcn_global_load_lds(
          (const __attribute__((address_space(1))) void*)(pAf[g] + ko),
          (__attribute__((address_space(3))) void*)(base + (g * 8 + w) * 1024),
          16, 0, 0);
  };
  auto stageB = [&](int buf, int pair) {
    char* base = lds + 65536 + buf * 32768;
    const int ko = pair << 6;                    // 64 bf16 per pair
#pragma unroll
    for (int g = 0; g < 4; ++g)
      __builtin_amdgcn_global_load_lds(
          (const __attribute__((address_space(1))) void*)(pBf[g] + ko),
          (__attribute__((address_space(3))) void*)(base + g * 8192 + w * 1024),
          16, 0, 0);
  };

  const int fr = lane & 15;
  const int kg = lane >> 4;

  f32x4 acc[8][4];
#pragma unroll
  for (int i = 0; i < 8; ++i)
#pragma unroll
    for (int j = 0; j < 4; ++j) acc[i][j] = (f32x4)0.0f;

  stageA(0, 0);
  stageB(0, 0);
  __syncthreads();

#pragma unroll 1
  for (int kt = 0; kt < 16; ++kt) {
    const int cur = kt & 1;            // A buffer
    const int bp = (kt >> 1) & 1;      // B buffer (per pair)
    if (kt < 15) stageA(cur ^ 1, kt + 1);
    if ((kt & 1) == 0 && kt < 14) stageB(bp ^ 1, (kt >> 1) + 1);

    const char* ldsA = lds + cur * 32768;
    const char* ldsB = lds + 65536 + bp * 32768;
    const int kk = (kt & 1) * 32;      // K offset within B pair buffer
    bf16x8 bfr[4];
#pragma unroll
    for (int n = 0; n < 4; ++n) {
      int rowB = ((n < 2) ? (wn * 32 + n * 16) : (128 + wn * 32 + (n - 2) * 16)) + fr;
      int sb = (kk * 2 + kg * 16) ^ ((rowB & 7) << 4);
      bfr[n] = *reinterpret_cast<const bf16x8*>(ldsB + rowB * 128 + sb);
    }
#pragma unroll
    for (int i = 0; i < 8; ++i) {
      int rowA = wm * 128 + i * 16 + fr;
      int s0 = (((2 * kg) ^ (fr & 7)) << 4);
      int s1 = (((2 * kg + 1) ^ (fr & 7)) << 4);
      f32x4 q0 = *reinterpret_cast<const f32x4*>(ldsA + rowA * 128 + s0);
      f32x4 q1 = *reinterpret_cast<const f32x4*>(ldsA + rowA * 128 + s1);
      uint4 u;
      u.x = cvtpk(q0[0], q0[1]);
      u.y = cvtpk(q0[2], q0[3]);
      u.z = cvtpk(q1[0], q1[1]);
      u.w = cvtpk(q1[2], q1[3]);
      bf16x8 af = *reinterpret_cast<bf16x8*>(&u);
#pragma unroll
      for (int j = 0; j < 4; ++j)
        acc[i][j] = __builtin_amdgcn_mfma_f32_16x16x32_bf16(af, bfr[j], acc[i][j], 0, 0, 0);
    }
    __syncthreads();   // one barrier per kt: drains staged loads, orders buffers
  }

  // ---------------- epilogue: pure-register a/b + wave-local chunk aggregates ----
  const float LOG2E = 1.44269504f;
#pragma unroll
  for (int n = 0; n < 2; ++n) {
    const int ch = wn * 32 + n * 16 + fr;
    float Am[8], Bm[8];
#pragma unroll
    for (int m = 0; m < 8; ++m) {
      float As = 1.0f, Bs = 0.0f;
#pragma unroll
      for (int r = 0; r < 4; ++r) {
        float hid = acc[m][n][r];
        float gat = acc[m][n + 2][r];
        float ex1 = __builtin_amdgcn_exp2f(gat * LOG2E);      // exp(gat)
        float a = __builtin_amdgcn_rcpf(1.0f + ex1);          // sigmoid(-gate)
        float z = 1.0f - a;                                   // sigmoid(gate)
        float ex2 = __builtin_amdgcn_exp2f(-hid * LOG2E);     // exp(-hid)
        float gn = __builtin_amdgcn_rcpf(1.0f + ex2);         // sigmoid(hid)
        float g = (hid >= 0.0f) ? (hid + 0.5f) : gn;
        float bb = z * g;
        int row = wm * 128 + 16 * m + 4 * kg + r;
        pk[(size_t)(m0 + row) * ND + n0 + ch] =
            ((uint32_t)f2bf(bb) << 16) | (uint32_t)f2bf(a);
        Bs = fmaf(a, Bs, bb);   // ordered: r ascending
        As *= a;
      }
      Am[m] = As; Bm[m] = Bs;
    }
    // ordered affine all-reduce across kg (4-row segments within 16-row groups)
#pragma unroll
    for (int m = 0; m < 8; ++m) {
      float pA_ = __shfl_xor(Am[m], 16);
      float pB_ = __shfl_xor(Bm[m], 16);
      Bm[m] = (kg & 1) ? fmaf(Am[m], pB_, Bm[m]) : fmaf(pA_, Bm[m], pB_);
      Am[m] *= pA_;
      pA_ = __shfl_xor(Am[m], 32);
      pB_ = __shfl_xor(Bm[m], 32);
      Bm[m] = (kg & 2) ? fmaf(Am[m], pB_, Bm[m]) : fmaf(pA_, Bm[m], pB_);
      Am[m] *= pA_;
    }
    // serial over the 8 16-row groups (ascending) -> full 128-row chunk aggregate
    float As = Am[0], Bs = Bm[0];
#pragma unroll
    for (int m = 1; m < 8; ++m) { Bs = fmaf(Am[m], Bs, Bm[m]); As *= Am[m]; }
    if (kg == 0) {
      size_t o = (size_t)(mblk * 2 + wm) * ND + n0 + ch;   // global chunk index
      aggA[o] = As;
      aggB[o] = Bs;
    }
  }
}

// ---------------- scan pass2: prefix + rescan, write out f32 ----------------
__global__ __launch_bounds__(256) void scan_pass2(const uint32_t* __restrict__ pk,
                                                  const float* __restrict__ aggA,
                                                  const float* __restrict__ aggB,
                                                  float* __restrict__ out,
                                                  float* __restrict__ nextp) {
  int bid = blockIdx.x;
  int b = bid >> 6;
  int c = bid & 63;
  int d2 = threadIdx.x;        // channel-pair 0..255

  float h0 = 0.0f, h1 = 0.0f;
  for (int cc = 0; cc < c; ++cc) {
    int o = (b * 64 + cc) * ND + d2 * 2;
    float2 Aa = *reinterpret_cast<const float2*>(&aggA[o]);
    float2 Bb = *reinterpret_cast<const float2*>(&aggB[o]);
    h0 = fmaf(Aa.x, h0, Bb.x);
    h1 = fmaf(Aa.y, h1, Bb.y);
  }
  size_t base = (size_t)(b * NS + c * 128) * ND + d2 * 2;
#pragma unroll 4
  for (int t = 0; t < 128; ++t) {
    size_t idx = base + (size_t)t * ND;
    uint2 v = *reinterpret_cast<const uint2*>(pk + idx);
    float a0 = __uint_as_float(v.x << 16);
    float b0 = __uint_as_float(v.x & 0xffff0000u);
    float a1 = __uint_as_float(v.y << 16);
    float b1 = __uint_as_float(v.y & 0xffff0000u);
    h0 = fmaf(a0, h0, b0);
    h1 = fmaf(a1, h1, b1);
    *reinterpret_cast<float2*>(&out[idx]) = make_float2(h0, h1);
  }
  if (c == 63) {
    *reinterpret_cast<float2*>(&nextp[b * ND + d2 * 2]) = make_float2(h0, h1);
  }
}

// ---------------- launcher ----------------
extern "C" void kernel_launch(void* const* d_in, const int* in_sizes, int n_in,
                              void* d_out, int out_size, void* d_ws, size_t ws_size,
                              hipStream_t stream) {
  const float* x = (const float*)d_in[0];   // (8, 8192, 512) f32
  const float* W = (const float*)d_in[1];   // (1024, 512) f32
  float* out = (float*)d_out;               // 33554432 + 4096 f32

  char* ws = (char*)d_ws;
  uint32_t* pk = (uint32_t*)ws;                                            // 128 MB
  unsigned short* wbf = (unsigned short*)(ws + (size_t)128 * 1024 * 1024); // 1 MB
  float* aggA = (float*)(ws + (size_t)129 * 1024 * 1024);                  // 1 MB
  float* aggB = (float*)(ws + (size_t)130 * 1024 * 1024);                  // 1 MB
  float* nextp = out + (size_t)NM * ND;

  cvt_bf16<<<256, 256, 0, stream>>>(W, wbf, (1024 * NK) / 8);
  gemm_ab<<<1024, 512, 0, stream>>>(x, wbf, pk, aggA, aggB);
  scan_pass2<<<512, 256, 0, stream>>>(pk, aggA, aggB, out, nextp);
}